// Round 5
// baseline (256.809 us; speedup 1.0000x reference)
//
#include <hip/hip_runtime.h>
#include <hip/hip_bf16.h>
#include <math.h>

#define B_   8
#define H_   16
#define BH_  (B_*H_)
#define LK_  4096
#define D_   128

#define SEG   16
#define KSEG  (LK_/SEG)     // 256 keys per score/context block

typedef __attribute__((ext_vector_type(8))) short bf16x8;
typedef __attribute__((ext_vector_type(4))) float f32x4;
typedef __attribute__((ext_vector_type(4))) unsigned int u32x4;

// ---------------- fast tanh (f32, ~1e-6 abs err) ----------------
__device__ __forceinline__ float fast_tanh(float x) {
    float ax = fabsf(x);
    float e  = __expf(2.0f * ax);
    float r  = 1.0f - __fdividef(2.0f, e + 1.0f);
    return copysignf(r, x);
}

// packed f32x2 -> bf16x2 (RNE), single VALU instr
__device__ __forceinline__ unsigned int cvtpk(float lo, float hi) {
    unsigned int r;
    asm("v_cvt_pk_bf16_f32 %0, %1, %2" : "=v"(r) : "v"(lo), "v"(hi));
    return r;
}

// f32 -> bf16 hi/lo split (hi = RNE bf16(x), lo = RNE bf16(x - hi)) — scalar path (pack kernel)
__device__ __forceinline__ void cvt_hilo(float x, unsigned short& h, unsigned short& l) {
    __hip_bfloat16 bh = __float2bfloat16(x);
    unsigned short hu = __builtin_bit_cast(unsigned short, bh);
    float hf = __uint_as_float((unsigned int)hu << 16);
    __hip_bfloat16 bl = __float2bfloat16(x - hf);
    h = hu;
    l = __builtin_bit_cast(unsigned short, bl);
}

// 8-wide hi/lo split via v_cvt_pk_bf16_f32: 24 VALU for 8 elements
__device__ __forceinline__ void cvt8(const float4 a, const float4 b, bf16x8& h, bf16x8& l) {
    unsigned int h0 = cvtpk(a.x, a.y);
    unsigned int h1 = cvtpk(a.z, a.w);
    unsigned int h2 = cvtpk(b.x, b.y);
    unsigned int h3 = cvtpk(b.z, b.w);
    float l0 = a.x - __uint_as_float(h0 << 16);
    float l1 = a.y - __uint_as_float(h0 & 0xFFFF0000u);
    float l2 = a.z - __uint_as_float(h1 << 16);
    float l3 = a.w - __uint_as_float(h1 & 0xFFFF0000u);
    float l4 = b.x - __uint_as_float(h2 << 16);
    float l5 = b.y - __uint_as_float(h2 & 0xFFFF0000u);
    float l6 = b.z - __uint_as_float(h3 << 16);
    float l7 = b.w - __uint_as_float(h3 & 0xFFFF0000u);
    u32x4 hv = {h0, h1, h2, h3};
    u32x4 lv = {cvtpk(l0, l1), cvtpk(l2, l3), cvtpk(l4, l5), cvtpk(l6, l7)};
    h = __builtin_bit_cast(bf16x8, hv);
    l = __builtin_bit_cast(bf16x8, lv);
}

// ---------------- kernel 0: pack W_pre into MFMA fragment order (hi/lo) ------
// idx = ((ks*8 + nt)*64 + lane)*8 + j ; k = ks*32 + (lane>>4)*8 + j ; n = nt*16 + (lane&15)
__global__ void pack_kernel(const float* __restrict__ Wpre,
                            unsigned short* __restrict__ Bhi,
                            unsigned short* __restrict__ Blo) {
    int idx  = blockIdx.x * 256 + threadIdx.x;      // 0..16383
    int j    = idx & 7;
    int lane = (idx >> 3) & 63;
    int nt   = (idx >> 9) & 7;
    int ks   = idx >> 12;
    int k    = ks * 32 + (lane >> 4) * 8 + j;
    int n    = nt * 16 + (lane & 15);
    unsigned short h, l;
    cvt_hilo(Wpre[k * D_ + n], h, l);
    Bhi[idx] = h;
    Blo[idx] = l;
}

// ---------------- kernel 1: tq[bh][e] = Q[bh]·W_q[:,e] ----------------
__global__ void tq_kernel(const float* __restrict__ Q,
                          const float* __restrict__ Wq,
                          float* __restrict__ tq) {
    int bh = blockIdx.x;
    int e  = threadIdx.x;
    const float* q = Q + bh * D_;
    float acc = 0.0f;
#pragma unroll 8
    for (int d = 0; d < D_; ++d)
        acc = fmaf(q[d], Wq[d * D_ + e], acc);
    tq[bh * D_ + e] = acc;
}

// ---------------- kernel 2: pre^T = W^T·K^T (+b) ; energy partials ------------
// grid (LK/256, BH), block 256 = 4 waves = (2 key-groups) x (2 e-halves).
// W frags register-resident; K streamed global->reg with DEPTH-2 prefetch
// (3 rotating buffers). NO barriers, NO LDS — waves fully independent.
// Energy partial per e-half: eh=0 -> ep0 (score region), eh=1 -> ep1 (ws).
__global__ void __launch_bounds__(256, 2)
main_kernel(const float* __restrict__ K,
            const unsigned short* __restrict__ Whi,
            const unsigned short* __restrict__ Wlo,
            const float* __restrict__ bpre,
            const float* __restrict__ Wv,
            const float* __restrict__ tqg,
            float* __restrict__ pre_out,
            float* __restrict__ ep0,
            float* __restrict__ ep1) {
    const int t    = threadIdx.x;
    const int lane = t & 63;
    const int wv_  = t >> 6;
    const int kg   = wv_ & 1;            // key group (32 keys within 64-key iter)
    const int eh   = wv_ >> 1;           // e half (64 cols)
    const int l15  = lane & 15;
    const int lg   = lane >> 4;
    const int bh   = blockIdx.y;
    const int kblk = blockIdx.x * 256;

    // ---- resident W fragments: this wave's e-half, all ks, hi+lo
    bf16x8 wfh[4][4], wfl[4][4];
#pragma unroll
    for (int ks = 0; ks < 4; ++ks)
#pragma unroll
        for (int et = 0; et < 4; ++et) {
            size_t idx = (((size_t)ks * 8 + eh * 4 + et) * 64 + lane) * 8;
            wfh[ks][et] = *(const bf16x8*)(Whi + idx);
            wfl[ks][et] = *(const bf16x8*)(Wlo + idx);
        }

    // ---- hoisted epilogue constants (per-wave e-range)
    float4 bpv[4], tqv[4], wvv[4];
#pragma unroll
    for (int et = 0; et < 4; ++et) {
        const int e0 = eh * 64 + et * 16 + lg * 4;
        bpv[et] = *(const float4*)(bpre + e0);
        tqv[et] = *(const float4*)(tqg + bh * D_ + e0);
        wvv[et] = *(const float4*)(Wv + e0);
    }

    // lane's K stream base: row = kblk + kg*32 + kt*16 + l15 ; d-offset lg*8
    const float* Kw = K + ((size_t)bh * LK_ + kblk + kg * 32 + l15) * D_ + lg * 8;

    float* epo = (eh == 0) ? ep0 : ep1;

    // ---- prologue: load stages 0 and 1 (stage s = it*4+ks)
    float4 rw[3][2][2];                  // [buf][kt][half]
#pragma unroll
    for (int s = 0; s < 2; ++s) {
        const int it0 = 0, ks0 = s;
#pragma unroll
        for (int kt = 0; kt < 2; ++kt) {
            const float* p = Kw + ((size_t)it0 * 64 + kt * 16) * D_ + ks0 * 32;
            rw[s][kt][0] = *(const float4*)p;
            rw[s][kt][1] = *(const float4*)(p + 4);
        }
    }

#pragma unroll
    for (int it = 0; it < 4; ++it) {
        f32x4 acc[2][4];
#pragma unroll
        for (int kt = 0; kt < 2; ++kt)
#pragma unroll
            for (int et = 0; et < 4; ++et)
                acc[kt][et] = (f32x4){0.f, 0.f, 0.f, 0.f};

#pragma unroll
        for (int ks = 0; ks < 4; ++ks) {
            const int s = it * 4 + ks;
            // issue loads 2 stages ahead
            if (s + 2 < 16) {
                const int s2  = s + 2;
                const int it2 = s2 >> 2, ks2 = s2 & 3, b2 = s2 % 3;
#pragma unroll
                for (int kt = 0; kt < 2; ++kt) {
                    const float* p = Kw + ((size_t)it2 * 64 + kt * 16) * D_ + ks2 * 32;
                    rw[b2][kt][0] = *(const float4*)p;
                    rw[b2][kt][1] = *(const float4*)(p + 4);
                }
            }
            // convert current raw -> bf16 hi/lo fragments (cvt_pk path)
            const int cb = s % 3;
            bf16x8 kh[2], kl[2];
            cvt8(rw[cb][0][0], rw[cb][0][1], kh[0], kl[0]);
            cvt8(rw[cb][1][0], rw[cb][1][1], kh[1], kl[1]);
            // 24 MFMAs: D[e][key] += Wfrag · Kfrag (3-product hi/lo split)
#pragma unroll
            for (int kt = 0; kt < 2; ++kt)
#pragma unroll
                for (int et = 0; et < 4; ++et) {
                    acc[kt][et] = __builtin_amdgcn_mfma_f32_16x16x32_bf16(wfh[ks][et], kh[kt], acc[kt][et], 0, 0, 0);
                    acc[kt][et] = __builtin_amdgcn_mfma_f32_16x16x32_bf16(wfl[ks][et], kh[kt], acc[kt][et], 0, 0, 0);
                    acc[kt][et] = __builtin_amdgcn_mfma_f32_16x16x32_bf16(wfh[ks][et], kl[kt], acc[kt][et], 0, 0, 0);
                }
        }

        // ---- epilogue: pre store (f32x4 NT) + energy partial (no barrier)
        const int kb = kblk + it * 64 + kg * 32;
#pragma unroll
        for (int kt = 0; kt < 2; ++kt) {
            float* pb = pre_out + ((size_t)bh * LK_ + kb + kt * 16 + l15) * D_ + eh * 64 + lg * 4;
            float ep = 0.0f;
#pragma unroll
            for (int et = 0; et < 4; ++et) {
                f32x4 a = acc[kt][et];
                f32x4 v;
                v[0] = a[0] + bpv[et].x;
                v[1] = a[1] + bpv[et].y;
                v[2] = a[2] + bpv[et].z;
                v[3] = a[3] + bpv[et].w;
                __builtin_nontemporal_store(v, (f32x4*)(pb + et * 16));
                ep = fmaf(fast_tanh(v[0] + tqv[et].x), wvv[et].x, ep);
                ep = fmaf(fast_tanh(v[1] + tqv[et].y), wvv[et].y, ep);
                ep = fmaf(fast_tanh(v[2] + tqv[et].z), wvv[et].z, ep);
                ep = fmaf(fast_tanh(v[3] + tqv[et].w), wvv[et].w, ep);
            }
            // reduce over the 4 lg groups (e dimension) within the wave
            ep += __shfl_xor(ep, 16, 64);
            ep += __shfl_xor(ep, 32, 64);
            if (lg == 0)
                epo[(size_t)bh * LK_ + kb + kt * 16 + l15] = ep;
        }
    }
}

// ---------------- kernel 3a: per-(b,h) masked max & sum(exp) ----------------
__global__ void ml_kernel(const float* __restrict__ ep0,
                          const float* __restrict__ ep1,
                          const int* __restrict__ mask,
                          float* __restrict__ ml) {
    const int bh = blockIdx.x;
    const int t  = threadIdx.x;
    const float* e0 = ep0 + (size_t)bh * LK_;
    const float* e1 = ep1 + (size_t)bh * LK_;
    const int*   m  = mask + (size_t)bh * LK_;

    float mx = -1e30f;
    for (int k = t; k < LK_; k += 256) {
        float v = m[k] ? -1.0e6f : (e0[k] + e1[k]);
        mx = fmaxf(mx, v);
    }
#pragma unroll
    for (int off = 32; off > 0; off >>= 1)
        mx = fmaxf(mx, __shfl_xor(mx, off, 64));
    __shared__ float wmax[4];
    if ((t & 63) == 0) wmax[t >> 6] = mx;
    __syncthreads();
    mx = fmaxf(fmaxf(wmax[0], wmax[1]), fmaxf(wmax[2], wmax[3]));

    float sum = 0.0f;
    for (int k = t; k < LK_; k += 256) {
        float v = m[k] ? -1.0e6f : (e0[k] + e1[k]);
        sum += __expf(v - mx);
    }
#pragma unroll
    for (int off = 32; off > 0; off >>= 1)
        sum += __shfl_xor(sum, off, 64);
    __shared__ float wsum[4];
    if ((t & 63) == 0) wsum[t >> 6] = sum;
    __syncthreads();
    if (t == 0) {
        ml[bh * 2]     = mx;
        ml[bh * 2 + 1] = wsum[0] + wsum[1] + wsum[2] + wsum[3];
    }
}

// ---------------- kernel 3b: score + partial context ----------------
// grid: (SEG, BH), block 256. KSEG=256: one score per thread, float4 V loads.
// Reads energy = ep0 + ep1; overwrites ep0 (score region) with final score.
__global__ void score_ctx_kernel(const float* __restrict__ ep1,
                                 const int* __restrict__ mask,
                                 const float* __restrict__ V,
                                 const float* __restrict__ ml,
                                 float* __restrict__ score_out,
                                 float* __restrict__ part) {
    const int seg = blockIdx.x;
    const int bh  = blockIdx.y;
    const int t   = threadIdx.x;
    const int k0  = seg * KSEG;

    __shared__ float sc[KSEG];
    __shared__ float pl[8][136];

    const float mx  = ml[bh * 2];
    const float inv = 1.0f / ml[bh * 2 + 1];

    {
        const size_t gi = (size_t)bh * LK_ + k0 + t;
        float v = mask[gi] ? -1.0e6f : (score_out[gi] + ep1[gi]);
        float s = __expf(v - mx) * inv;
        sc[t] = s;
        score_out[gi] = s;
    }
    __syncthreads();

    const int d4 = t & 31;           // float4 column
    const int g  = t >> 5;           // k-group 0..7
    const float* Vb = V + ((size_t)bh * LK_ + k0) * D_ + d4 * 4;
    float4 a = make_float4(0.f, 0.f, 0.f, 0.f);
#pragma unroll 4
    for (int kk = g; kk < KSEG; kk += 8) {
        float4 vv = *(const float4*)(Vb + (size_t)kk * D_);
        float s = sc[kk];
        a.x = fmaf(s, vv.x, a.x);
        a.y = fmaf(s, vv.y, a.y);
        a.z = fmaf(s, vv.z, a.z);
        a.w = fmaf(s, vv.w, a.w);
    }
    *(float4*)&pl[g][d4 * 4] = a;
    __syncthreads();

    if (t < 128) {
        float s = 0.0f;
#pragma unroll
        for (int gg = 0; gg < 8; ++gg)
            s += pl[gg][t];
        part[((size_t)bh * SEG + seg) * D_ + t] = s;
    }
}

// ---------------- kernel 3c: combine partial contexts ----------------
__global__ void combine_kernel(const float* __restrict__ part,
                               float* __restrict__ ctx) {
    const int bh = blockIdx.x;
    const int d  = threadIdx.x;
    float s = 0.0f;
#pragma unroll
    for (int g = 0; g < SEG; ++g)
        s += part[((size_t)bh * SEG + g) * D_ + d];
    ctx[bh * D_ + d] = s;
}

// ---------------- launch ----------------
extern "C" void kernel_launch(void* const* d_in, const int* in_sizes, int n_in,
                              void* d_out, int out_size, void* d_ws, size_t ws_size,
                              hipStream_t stream) {
    const float* Q    = (const float*)d_in[0];
    const float* K    = (const float*)d_in[1];
    const float* V    = (const float*)d_in[2];
    const int*   mask = (const int*)  d_in[3];
    // d_in[4] = scale (unused by reference)
    const float* Wpre = (const float*)d_in[5];
    const float* bpre = (const float*)d_in[6];
    const float* Wq   = (const float*)d_in[7];
    const float* Wv   = (const float*)d_in[8];

    float* out   = (float*)d_out;
    float* ctx   = out;                           // [BH][D]
    float* score = out + (size_t)BH_ * D_;        // [BH][LK] — holds ep0 then score
    float* pre   = score + (size_t)BH_ * LK_;     // [BH][LK][D]

    float* w    = (float*)d_ws;
    float* tq   = w;                              // BH*D floats
    float* ml   = tq + (size_t)BH_ * D_;          // BH*2
    float* part = ml + 2 * BH_;                   // BH*SEG*D
    unsigned short* Whi = (unsigned short*)(part + (size_t)BH_ * SEG * D_); // 16384
    unsigned short* Wlo = Whi + 16384;                                      // 16384
    float* ep1  = (float*)(Wlo + 16384);          // BH*LK (2 MB)

    hipLaunchKernelGGL(pack_kernel, dim3(64), dim3(256), 0, stream, Wpre, Whi, Wlo);
    hipLaunchKernelGGL(tq_kernel, dim3(BH_), dim3(D_), 0, stream, Q, Wq, tq);
    hipLaunchKernelGGL(main_kernel, dim3(LK_ / 256, BH_), dim3(256), 0, stream,
                       K, Whi, Wlo, bpre, Wv, tq, pre, score, ep1);
    hipLaunchKernelGGL(ml_kernel, dim3(BH_), dim3(256), 0, stream, score, ep1, mask, ml);
    hipLaunchKernelGGL(score_ctx_kernel, dim3(SEG, BH_), dim3(256), 0, stream,
                       ep1, mask, V, ml, score, part);
    hipLaunchKernelGGL(combine_kernel, dim3(BH_), dim3(D_), 0, stream, part, ctx);
}

// Round 7
// 236.286 us; speedup vs baseline: 1.0869x; 1.0869x over previous
//
#include <hip/hip_runtime.h>
#include <hip/hip_bf16.h>
#include <math.h>

#define B_   8
#define H_   16
#define BH_  (B_*H_)
#define LK_  4096
#define D_   128

#define SEG   16
#define KSEG  (LK_/SEG)     // 256 keys per score/context block

typedef __attribute__((ext_vector_type(8))) short bf16x8;
typedef __attribute__((ext_vector_type(4))) float f32x4;
typedef __attribute__((ext_vector_type(4))) unsigned int u32x4;

// ---------------- fast tanh (f32, ~1e-6 abs err) ----------------
__device__ __forceinline__ float fast_tanh(float x) {
    float ax = fabsf(x);
    float e  = __expf(2.0f * ax);
    float r  = 1.0f - __fdividef(2.0f, e + 1.0f);
    return copysignf(r, x);
}

// packed f32x2 -> bf16x2 (RNE), single VALU instr
__device__ __forceinline__ unsigned int cvtpk(float lo, float hi) {
    unsigned int r;
    asm("v_cvt_pk_bf16_f32 %0, %1, %2" : "=v"(r) : "v"(lo), "v"(hi));
    return r;
}

// scalar f32 -> bf16 RNE (pack kernel only)
__device__ __forceinline__ unsigned short cvt_hi(float x) {
    __hip_bfloat16 bh = __float2bfloat16(x);
    return __builtin_bit_cast(unsigned short, bh);
}

// 8-wide hi/lo split via v_cvt_pk_bf16_f32: (kh + kl) == x to ~2^-16 rel
__device__ __forceinline__ void cvt8(const float4 a, const float4 b, bf16x8& h, bf16x8& l) {
    unsigned int h0 = cvtpk(a.x, a.y);
    unsigned int h1 = cvtpk(a.z, a.w);
    unsigned int h2 = cvtpk(b.x, b.y);
    unsigned int h3 = cvtpk(b.z, b.w);
    float l0 = a.x - __uint_as_float(h0 << 16);
    float l1 = a.y - __uint_as_float(h0 & 0xFFFF0000u);
    float l2 = a.z - __uint_as_float(h1 << 16);
    float l3 = a.w - __uint_as_float(h1 & 0xFFFF0000u);
    float l4 = b.x - __uint_as_float(h2 << 16);
    float l5 = b.y - __uint_as_float(h2 & 0xFFFF0000u);
    float l6 = b.z - __uint_as_float(h3 << 16);
    float l7 = b.w - __uint_as_float(h3 & 0xFFFF0000u);
    u32x4 hv = {h0, h1, h2, h3};
    u32x4 lv = {cvtpk(l0, l1), cvtpk(l2, l3), cvtpk(l4, l5), cvtpk(l6, l7)};
    h = __builtin_bit_cast(bf16x8, hv);
    l = __builtin_bit_cast(bf16x8, lv);
}

// ---------------- kernel 0: pack W_pre (hi only) into MFMA fragment order ----
// idx = ((ks*8 + nt)*64 + lane)*8 + j ; k = ks*32 + (lane>>4)*8 + j ; n = nt*16 + (lane&15)
__global__ void pack_kernel(const float* __restrict__ Wpre,
                            unsigned short* __restrict__ Whi) {
    int idx  = blockIdx.x * 256 + threadIdx.x;      // 0..16383
    int j    = idx & 7;
    int lane = (idx >> 3) & 63;
    int nt   = (idx >> 9) & 7;
    int ks   = idx >> 12;
    int k    = ks * 32 + (lane >> 4) * 8 + j;
    int n    = nt * 16 + (lane & 15);
    Whi[idx] = cvt_hi(Wpre[k * D_ + n]);
}

// ---------------- kernel 1: tq[bh][e] = Q[bh]·W_q[:,e] ----------------
__global__ void tq_kernel(const float* __restrict__ Q,
                          const float* __restrict__ Wq,
                          float* __restrict__ tq) {
    int bh = blockIdx.x;
    int e  = threadIdx.x;
    const float* q = Q + bh * D_;
    float acc = 0.0f;
#pragma unroll 8
    for (int d = 0; d < D_; ++d)
        acc = fmaf(q[d], Wq[d * D_ + e], acc);
    tq[bh * D_ + e] = acc;
}

// ---------------- kernel 2: pre^T = W^T·K^T (+b) ; energy partials ------------
// grid (LK/256, BH), block 256 = 4 waves = (2 key-groups) x (2 e-halves).
// W-hi in LDS (32 KB, shared); K streamed global->reg with depth-2 prefetch.
// 2-product split: (Khi + Klo) · Whi. No per-iter barriers.
__global__ void __launch_bounds__(256, 3)
main_kernel(const float* __restrict__ K,
            const unsigned short* __restrict__ Whi,
            const float* __restrict__ bpre,
            const float* __restrict__ Wv,
            const float* __restrict__ tqg,
            float* __restrict__ pre_out,
            float* __restrict__ ep0,
            float* __restrict__ ep1) {
    const int t    = threadIdx.x;
    const int lane = t & 63;
    const int wv_  = t >> 6;
    const int kg   = wv_ & 1;            // key group (32 keys within 64-key iter)
    const int eh   = wv_ >> 1;           // e half (64 cols)
    const int l15  = lane & 15;
    const int lg   = lane >> 4;
    const int bh   = blockIdx.y;
    const int kblk = blockIdx.x * 256;

    __shared__ unsigned short Wlds[16384];   // 32 KB: W-hi fragment-ordered
    {
        // 16384 shorts = 2048 u32x4 -> 8 iterations of 256 threads
        const u32x4* src = (const u32x4*)Whi;
        u32x4* dst = (u32x4*)Wlds;
#pragma unroll
        for (int i = 0; i < 8; ++i)
            dst[i * 256 + t] = src[i * 256 + t];
    }
    __syncthreads();

    // lane's K stream base: row = kblk + kg*32 + kt*16 + l15 ; d-offset lg*8
    const float* Kw = K + ((size_t)bh * LK_ + kblk + kg * 32 + l15) * D_ + lg * 8;
    float* epo = (eh == 0) ? ep0 : ep1;
    const unsigned short* wb = Wlds + (size_t)(eh * 4) * 512 + (size_t)lane * 8;

    // ---- prologue: load stages 0 and 1 (stage s = it*4+ks)
    float4 rw[3][2][2];                  // [buf][kt][half]
#pragma unroll
    for (int s = 0; s < 2; ++s) {
#pragma unroll
        for (int kt = 0; kt < 2; ++kt) {
            const float* p = Kw + ((size_t)kt * 16) * D_ + s * 32;
            rw[s][kt][0] = *(const float4*)p;
            rw[s][kt][1] = *(const float4*)(p + 4);
        }
    }

#pragma unroll
    for (int it = 0; it < 4; ++it) {
        f32x4 acc[2][4];
#pragma unroll
        for (int kt = 0; kt < 2; ++kt)
#pragma unroll
            for (int et = 0; et < 4; ++et)
                acc[kt][et] = (f32x4){0.f, 0.f, 0.f, 0.f};

#pragma unroll
        for (int ks = 0; ks < 4; ++ks) {
            const int s = it * 4 + ks;
            // issue loads 2 stages ahead
            if (s + 2 < 16) {
                const int s2  = s + 2;
                const int it2 = s2 >> 2, ks2 = s2 & 3, b2 = s2 % 3;
#pragma unroll
                for (int kt = 0; kt < 2; ++kt) {
                    const float* p = Kw + ((size_t)it2 * 64 + kt * 16) * D_ + ks2 * 32;
                    rw[b2][kt][0] = *(const float4*)p;
                    rw[b2][kt][1] = *(const float4*)(p + 4);
                }
            }
            // W-hi fragments for this ks from LDS (lane-linear b128, conflict-free)
            bf16x8 wf[4];
#pragma unroll
            for (int et = 0; et < 4; ++et)
                wf[et] = *(const bf16x8*)(wb + ((size_t)ks * 8 + et) * 512);
            // convert current raw K -> bf16 hi/lo fragments
            const int cb = s % 3;
            bf16x8 kh[2], kl[2];
            cvt8(rw[cb][0][0], rw[cb][0][1], kh[0], kl[0]);
            cvt8(rw[cb][1][0], rw[cb][1][1], kh[1], kl[1]);
            // 16 MFMAs: D[e][key] += Whi · (Khi + Klo)
#pragma unroll
            for (int kt = 0; kt < 2; ++kt)
#pragma unroll
                for (int et = 0; et < 4; ++et) {
                    acc[kt][et] = __builtin_amdgcn_mfma_f32_16x16x32_bf16(wf[et], kh[kt], acc[kt][et], 0, 0, 0);
                    acc[kt][et] = __builtin_amdgcn_mfma_f32_16x16x32_bf16(wf[et], kl[kt], acc[kt][et], 0, 0, 0);
                }
        }

        // ---- epilogue: pre store (f32x4 NT) + energy partial (no barrier)
        const int kb = kblk + it * 64 + kg * 32;
        float ep[2] = {0.0f, 0.0f};
#pragma unroll
        for (int et = 0; et < 4; ++et) {
            const int e0 = eh * 64 + et * 16 + lg * 4;
            const float4 bp = *(const float4*)(bpre + e0);
            const float4 tq = *(const float4*)(tqg + bh * D_ + e0);
            const float4 wv = *(const float4*)(Wv + e0);
#pragma unroll
            for (int kt = 0; kt < 2; ++kt) {
                f32x4 a = acc[kt][et];
                f32x4 v;
                v[0] = a[0] + bp.x;
                v[1] = a[1] + bp.y;
                v[2] = a[2] + bp.z;
                v[3] = a[3] + bp.w;
                float* pb = pre_out + ((size_t)bh * LK_ + kb + kt * 16 + l15) * D_ + e0;
                __builtin_nontemporal_store(v, (f32x4*)pb);
                ep[kt] = fmaf(fast_tanh(v[0] + tq.x), wv.x, ep[kt]);
                ep[kt] = fmaf(fast_tanh(v[1] + tq.y), wv.y, ep[kt]);
                ep[kt] = fmaf(fast_tanh(v[2] + tq.z), wv.z, ep[kt]);
                ep[kt] = fmaf(fast_tanh(v[3] + tq.w), wv.w, ep[kt]);
            }
        }
#pragma unroll
        for (int kt = 0; kt < 2; ++kt) {
            float v = ep[kt];
            v += __shfl_xor(v, 16, 64);
            v += __shfl_xor(v, 32, 64);
            if (lg == 0)
                epo[(size_t)bh * LK_ + kb + kt * 16 + l15] = v;
        }
    }
}

// ---------------- kernel 3a: per-(b,h) masked max & sum(exp) ----------------
__global__ void ml_kernel(const float* __restrict__ ep0,
                          const float* __restrict__ ep1,
                          const int* __restrict__ mask,
                          float* __restrict__ ml) {
    const int bh = blockIdx.x;
    const int t  = threadIdx.x;
    const float* e0 = ep0 + (size_t)bh * LK_;
    const float* e1 = ep1 + (size_t)bh * LK_;
    const int*   m  = mask + (size_t)bh * LK_;

    float mx = -1e30f;
    for (int k = t; k < LK_; k += 256) {
        float v = m[k] ? -1.0e6f : (e0[k] + e1[k]);
        mx = fmaxf(mx, v);
    }
#pragma unroll
    for (int off = 32; off > 0; off >>= 1)
        mx = fmaxf(mx, __shfl_xor(mx, off, 64));
    __shared__ float wmax[4];
    if ((t & 63) == 0) wmax[t >> 6] = mx;
    __syncthreads();
    mx = fmaxf(fmaxf(wmax[0], wmax[1]), fmaxf(wmax[2], wmax[3]));

    float sum = 0.0f;
    for (int k = t; k < LK_; k += 256) {
        float v = m[k] ? -1.0e6f : (e0[k] + e1[k]);
        sum += __expf(v - mx);
    }
#pragma unroll
    for (int off = 32; off > 0; off >>= 1)
        sum += __shfl_xor(sum, off, 64);
    __shared__ float wsum[4];
    if ((t & 63) == 0) wsum[t >> 6] = sum;
    __syncthreads();
    if (t == 0) {
        ml[bh * 2]     = mx;
        ml[bh * 2 + 1] = wsum[0] + wsum[1] + wsum[2] + wsum[3];
    }
}

// ---------------- kernel 3b: score + partial context ----------------
// grid: (SEG, BH), block 256. KSEG=256: one score per thread, float4 V loads.
// Reads energy = ep0 + ep1; overwrites ep0 (score region) with final score.
__global__ void score_ctx_kernel(const float* __restrict__ ep1,
                                 const int* __restrict__ mask,
                                 const float* __restrict__ V,
                                 const float* __restrict__ ml,
                                 float* __restrict__ score_out,
                                 float* __restrict__ part) {
    const int seg = blockIdx.x;
    const int bh  = blockIdx.y;
    const int t   = threadIdx.x;
    const int k0  = seg * KSEG;

    __shared__ float sc[KSEG];
    __shared__ float pl[8][136];

    const float mx  = ml[bh * 2];
    const float inv = 1.0f / ml[bh * 2 + 1];

    {
        const size_t gi = (size_t)bh * LK_ + k0 + t;
        float v = mask[gi] ? -1.0e6f : (score_out[gi] + ep1[gi]);
        float s = __expf(v - mx) * inv;
        sc[t] = s;
        score_out[gi] = s;
    }
    __syncthreads();

    const int d4 = t & 31;           // float4 column
    const int g  = t >> 5;           // k-group 0..7
    const float* Vb = V + ((size_t)bh * LK_ + k0) * D_ + d4 * 4;
    float4 a = make_float4(0.f, 0.f, 0.f, 0.f);
#pragma unroll 4
    for (int kk = g; kk < KSEG; kk += 8) {
        float4 vv = *(const float4*)(Vb + (size_t)kk * D_);
        float s = sc[kk];
        a.x = fmaf(s, vv.x, a.x);
        a.y = fmaf(s, vv.y, a.y);
        a.z = fmaf(s, vv.z, a.z);
        a.w = fmaf(s, vv.w, a.w);
    }
    *(float4*)&pl[g][d4 * 4] = a;
    __syncthreads();

    if (t < 128) {
        float s = 0.0f;
#pragma unroll
        for (int gg = 0; gg < 8; ++gg)
            s += pl[gg][t];
        part[((size_t)bh * SEG + seg) * D_ + t] = s;
    }
}

// ---------------- kernel 3c: combine partial contexts ----------------
__global__ void combine_kernel(const float* __restrict__ part,
                               float* __restrict__ ctx) {
    const int bh = blockIdx.x;
    const int d  = threadIdx.x;
    float s = 0.0f;
#pragma unroll
    for (int g = 0; g < SEG; ++g)
        s += part[((size_t)bh * SEG + g) * D_ + d];
    ctx[bh * D_ + d] = s;
}

// ---------------- launch ----------------
extern "C" void kernel_launch(void* const* d_in, const int* in_sizes, int n_in,
                              void* d_out, int out_size, void* d_ws, size_t ws_size,
                              hipStream_t stream) {
    const float* Q    = (const float*)d_in[0];
    const float* K    = (const float*)d_in[1];
    const float* V    = (const float*)d_in[2];
    const int*   mask = (const int*)  d_in[3];
    // d_in[4] = scale (unused by reference)
    const float* Wpre = (const float*)d_in[5];
    const float* bpre = (const float*)d_in[6];
    const float* Wq   = (const float*)d_in[7];
    const float* Wv   = (const float*)d_in[8];

    float* out   = (float*)d_out;
    float* ctx   = out;                           // [BH][D]
    float* score = out + (size_t)BH_ * D_;        // [BH][LK] — holds ep0 then score
    float* pre   = score + (size_t)BH_ * LK_;     // [BH][LK][D]

    float* w    = (float*)d_ws;
    float* tq   = w;                              // BH*D floats
    float* ml   = tq + (size_t)BH_ * D_;          // BH*2
    float* part = ml + 2 * BH_;                   // BH*SEG*D
    unsigned short* Whi = (unsigned short*)(part + (size_t)BH_ * SEG * D_); // 16384
    float* ep1  = (float*)(Whi + 16384);          // BH*LK (2 MB)

    hipLaunchKernelGGL(pack_kernel, dim3(64), dim3(256), 0, stream, Wpre, Whi);
    hipLaunchKernelGGL(tq_kernel, dim3(BH_), dim3(D_), 0, stream, Q, Wq, tq);
    hipLaunchKernelGGL(main_kernel, dim3(LK_ / 256, BH_), dim3(256), 0, stream,
                       K, Whi, bpre, Wv, tq, pre, score, ep1);
    hipLaunchKernelGGL(ml_kernel, dim3(BH_), dim3(256), 0, stream, score, ep1, mask, ml);
    hipLaunchKernelGGL(score_ctx_kernel, dim3(SEG, BH_), dim3(256), 0, stream,
                       ep1, mask, V, ml, score, part);
    hipLaunchKernelGGL(combine_kernel, dim3(BH_), dim3(D_), 0, stream, part, ctx);
}